// Round 10
// baseline (90.065 us; speedup 1.0000x reference)
//
#include <hip/hip_runtime.h>

#define NR 4096      // rows per batch
#define DD 512       // feature dim
#define TWO_N 8192
#define MT 64        // 8192/128 tiles per dim
#define NTILES 2080  // MT*(MT+1)/2
#define CHUNK 260    // NTILES/8 per XCD

using bf16x8 = __attribute__((ext_vector_type(8))) short;   // 8 bf16 in 4 VGPRs
using f32x4  = __attribute__((ext_vector_type(4))) float;

__device__ __forceinline__ unsigned short f2bf(float f) {
    union { float f; unsigned u; } v; v.f = f;
    unsigned r = v.u + 0x7fff + ((v.u >> 16) & 1);   // round-to-nearest-even
    return (unsigned short)(r >> 16);
}

// Kernel 1: L2-normalize rows of A and B -> bf16 X = [nA; nB], fp32 d12[i] = nA_i . nB_i.
// Also zeroes S[8192] (2 elements per block).
__global__ __launch_bounds__(256) void ntx_nrm_kernel(const float* __restrict__ A,
                                                      const float* __restrict__ B,
                                                      unsigned short* __restrict__ X,
                                                      float* __restrict__ d12,
                                                      float* __restrict__ S) {
    const int row = blockIdx.x;
    const int t = threadIdx.x;            // 256 threads, 2 elems each
    const int lane = t & 63, wid = t >> 6;

    if (t < 2) S[row * 2 + t] = 0.f;

    const float2 av = *(const float2*)(A + row * DD + 2 * t);
    const float2 bv = *(const float2*)(B + row * DD + 2 * t);
    float sa = av.x * av.x + av.y * av.y;
    float sb = bv.x * bv.x + bv.y * bv.y;
#pragma unroll
    for (int o = 32; o; o >>= 1) { sa += __shfl_down(sa, o); sb += __shfl_down(sb, o); }

    __shared__ float red[12];
    if (lane == 0) { red[wid] = sa; red[4 + wid] = sb; }
    __syncthreads();
    const float ta = red[0] + red[1] + red[2] + red[3];
    const float tb = red[4] + red[5] + red[6] + red[7];
    const float ra = 1.f / fmaxf(sqrtf(ta), 1e-8f);
    const float rb = 1.f / fmaxf(sqrtf(tb), 1e-8f);
    const float nax = av.x * ra, nay = av.y * ra;
    const float nbx = bv.x * rb, nby = bv.y * rb;

    *(unsigned*)(X + row * DD + 2 * t) =
        (unsigned)f2bf(nax) | ((unsigned)f2bf(nay) << 16);
    *(unsigned*)(X + (NR + row) * DD + 2 * t) =
        (unsigned)f2bf(nbx) | ((unsigned)f2bf(nby) << 16);

    float dt = nax * nbx + nay * nby;
#pragma unroll
    for (int o = 32; o; o >>= 1) dt += __shfl_down(dt, o);
    if (lane == 0) red[8 + wid] = dt;
    __syncthreads();
    if (t == 0) d12[row] = red[8] + red[9] + red[10] + red[11];
}

// Kernel 2: logits[r,c] = 2 * X_r . Z_c, Z_c = X_{c^4096}.
// Symmetry: compute only u<=v in (u,v)=(i, j^32) tile coords (2080 tiles),
// supertile-major + XCD-contiguous remap (round-7 verified).
// Round-10: BK=32 (32 KB LDS -> 4-5 blocks/CU) with CONFLICT-FREE slot swizzle
// phys_slot = slot ^ ((row>>1)&3)  (bank quad = (row&1)*16 + slot*4; 16-lane frag
// groups spread 8 quads = 2-way = free). Rule-21 both-sides: linear DMA dest +
// inverse-swizzled global source + swizzled read. Counted-vmcnt 2-deep pipeline
// (round-8 verified) + T5 setprio around the MFMA cluster.
__global__ __launch_bounds__(256) void ntx_gemm_lse_kernel(const unsigned short* __restrict__ X,
                                                           float* __restrict__ S) {
    // ---- bid -> XCD-contiguous supertile-ordered sid -> (u,v) ----
    const int bid = blockIdx.x;
    const int sid = (bid & 7) * CHUNK + (bid >> 3);
    int u, v;
    if (sid < 1792) {                    // off-diagonal supertile (U<V): 28 x 64
        const int s = sid >> 6, loc = sid & 63;
        int U = 0;
        while (7 * (U + 1) - (U + 1) * U / 2 <= s) ++U;      // offExcl(U+1) <= s
        const int V = U + 1 + (s - (7 * U - U * (U - 1) / 2));
        u = U * 8 + (loc >> 3);
        v = V * 8 + (loc & 7);
    } else {                             // diagonal supertile (U==V): 8 x 36, lu<=lv
        const int s2 = sid - 1792;
        const int U = s2 / 36, loc = s2 % 36;
        int lu = 0;
        while ((lu + 1) * 8 - (lu + 1) * lu / 2 <= loc) ++lu; // offIncl(lu+1) <= loc
        const int lv = lu + (loc - (lu * 8 - lu * (lu - 1) / 2));
        u = U * 8 + lu;
        v = U * 8 + lv;
    }
    const bool fixedTile = (u == v);
    const int rowTile = u * 128, colTile = (v ^ 32) * 128;

    __shared__ unsigned short As[2][128 * 32];   // 2 x 8 KB
    __shared__ unsigned short Bs[2][128 * 32];

    const int t = threadIdx.x;
    const int lane = t & 63, wid = t >> 6;
    const int waveRow = wid >> 1, waveCol = wid & 1;
    const int lr = lane & 15, grp = lane >> 4;
    const int swr = (lr >> 1) & 3;       // read-side swizzle key ((row>>1)&3, m-independent)
    const int kslot = (grp ^ swr) * 8;   // physical 16B slot (in ushorts) for this lane's frag

    f32x4 acc[4][4] = {};

    // staging: wave wid fills 1KB chunks ci=wid*2+q (16 rows of 64B).
    // lane l -> row = ci*16 + l/4, phys slot = l&3, LDS ushort idx = ci*512 + l*8.
    // inverse source swizzle: phys p at row r holds logical p^((r>>1)&3);
    // (r>>1)&3 = (l>>3)&3 here, so source col = kt + ((l&3)^((l>>3)&3))*8 elems.
    const int srow = lane >> 2;                              // 0..15 within chunk
    const int scol = ((lane & 3) ^ ((lane >> 3) & 3)) * 8;   // swizzled source col (elems)

    auto STAGE = [&](int sel, int kt) {  // 4 VMEM instructions per wave
#pragma unroll
        for (int q = 0; q < 2; ++q) {
            const int ci = wid * 2 + q;
            const int r  = ci * 16 + srow;
            const int lo = ci * 512 + lane * 8;       // ushort index of lane's 16B slot
            __builtin_amdgcn_global_load_lds(
                (const __attribute__((address_space(1))) unsigned*)(X + (size_t)(rowTile + r) * DD + kt + scol),
                (__attribute__((address_space(3))) unsigned*)&As[sel][lo], 16, 0, 0);
            __builtin_amdgcn_global_load_lds(
                (const __attribute__((address_space(1))) unsigned*)(X + (size_t)((colTile + r) ^ NR) * DD + kt + scol),
                (__attribute__((address_space(3))) unsigned*)&Bs[sel][lo], 16, 0, 0);
        }
    };

    auto COMPUTE = [&](int sel) {
        bf16x8 af[4], bfr[4];
#pragma unroll
        for (int m = 0; m < 4; ++m)
            af[m] = *(const bf16x8*)&As[sel][(waveRow * 64 + m * 16 + lr) * 32 + kslot];
#pragma unroll
        for (int n = 0; n < 4; ++n)
            bfr[n] = *(const bf16x8*)&Bs[sel][(waveCol * 64 + n * 16 + lr) * 32 + kslot];
        __builtin_amdgcn_s_setprio(1);   // T5: favor this wave while it drains MFMAs
#pragma unroll
        for (int m = 0; m < 4; ++m)
#pragma unroll
            for (int n = 0; n < 4; ++n)
                acc[m][n] = __builtin_amdgcn_mfma_f32_16x16x32_bf16(af[m], bfr[n], acc[m][n], 0, 0, 0);
        __builtin_amdgcn_s_setprio(0);
    };

    // ---- 2-deep counted-vmcnt pipeline over 16 K-tiles (BK=32) ----
    STAGE(0, 0);                        // 4 outstanding (buf0)
    STAGE(1, 32);                       // 8 outstanding (buf0+buf1)
#pragma unroll
    for (int i = 0; i < 16; ++i) {
        const int cur = i & 1;
        if (i < 15) asm volatile("s_waitcnt vmcnt(4)" ::: "memory");  // my buf[cur] loads done
        else        asm volatile("s_waitcnt vmcnt(0)" ::: "memory");  // tail
        __builtin_amdgcn_s_barrier();   // all waves' buf[cur] writes landed
        COMPUTE(cur);
        if (i < 14) {
            asm volatile("s_waitcnt lgkmcnt(0)" ::: "memory");        // my ds_reads of buf[cur] done
            __builtin_amdgcn_s_barrier();                             // everyone's done reading buf[cur]
            STAGE(cur, (i + 2) * 32);   // refill 2 ahead; back to 8 outstanding
        }
    }

    // ---- Epilogue ----
    // C/D layout: col = lane&15 (lr), row = grp*4 + reg.
    // 1) in-place: acc <- exp(2*acc), masked to 0 on fixed-tile local diagonal
#pragma unroll
    for (int m = 0; m < 4; ++m)
#pragma unroll
        for (int n = 0; n < 4; ++n)
#pragma unroll
            for (int reg = 0; reg < 4; ++reg) {
                const int R = rowTile + waveRow * 64 + m * 16 + grp * 4 + reg;
                const int C = colTile + waveCol * 64 + n * 16 + lr;
                const bool masked = fixedTile && (C == (R ^ NR));
                acc[m][n][reg] = masked ? 0.f : __expf(acc[m][n][reg] * 2.0f);
            }

    // 2) row sums -> S[R]
#pragma unroll
    for (int m = 0; m < 4; ++m)
#pragma unroll
        for (int reg = 0; reg < 4; ++reg) {
            float rs = acc[m][0][reg] + acc[m][1][reg] + acc[m][2][reg] + acc[m][3][reg];
            rs += __shfl_xor(rs, 1);
            rs += __shfl_xor(rs, 2);
            rs += __shfl_xor(rs, 4);
            rs += __shfl_xor(rs, 8);
            if (lr == 0) {
                const int R = rowTile + waveRow * 64 + m * 16 + grp * 4 + reg;
                atomicAdd(&S[R], rs);
            }
        }

    // 3) mirror col sums -> S[C^N]  (skip on fixed tiles: they'd double-count)
    if (!fixedTile) {
#pragma unroll
        for (int n = 0; n < 4; ++n) {
            float cs = 0.f;
#pragma unroll
            for (int m = 0; m < 4; ++m)
#pragma unroll
                for (int reg = 0; reg < 4; ++reg)
                    cs += acc[m][n][reg];
            cs += __shfl_xor(cs, 16);
            cs += __shfl_xor(cs, 32);
            if (grp == 0) {
                const int C = colTile + waveCol * 64 + n * 16 + lr;
                atomicAdd(&S[C ^ NR], cs);
            }
        }
    }
}

// Kernel 3: loss = mean_r( log(S[r]) - 2*d12[r mod N] ), float32 scalar out.
__global__ __launch_bounds__(256) void ntx_loss_kernel(const float* __restrict__ S,
                                                       const float* __restrict__ d12,
                                                       float* __restrict__ out) {
    const int t = threadIdx.x;
    float a = 0.f;
    for (int r = t; r < TWO_N; r += 256)
        a += __logf(S[r]) - 2.0f * d12[r & (NR - 1)];
    const int lane = t & 63, wid = t >> 6;
#pragma unroll
    for (int o = 32; o; o >>= 1) a += __shfl_down(a, o);
    __shared__ float red[4];
    if (lane == 0) red[wid] = a;
    __syncthreads();
    if (t == 0) out[0] = (red[0] + red[1] + red[2] + red[3]) * (1.f / (float)TWO_N);
}

extern "C" void kernel_launch(void* const* d_in, const int* in_sizes, int n_in,
                              void* d_out, int out_size, void* d_ws, size_t ws_size,
                              hipStream_t stream) {
    const float* A = (const float*)d_in[0];
    const float* B = (const float*)d_in[1];

    // workspace layout
    unsigned short* X = (unsigned short*)d_ws;                    // 8192*512*2 = 8 MB
    float* S   = (float*)((char*)d_ws + (size_t)TWO_N * DD * 2);  // 32 KB
    float* d12 = (float*)((char*)S + (size_t)TWO_N * 4);          // 16 KB

    ntx_nrm_kernel<<<NR, 256, 0, stream>>>(A, B, X, d12, S);

    ntx_gemm_lse_kernel<<<NTILES, 256, 0, stream>>>(X, S);

    ntx_loss_kernel<<<1, 256, 0, stream>>>(S, d12, (float*)d_out);
}

// Round 11
// 89.337 us; speedup vs baseline: 1.0082x; 1.0082x over previous
//
#include <hip/hip_runtime.h>

#define NR 4096      // rows per batch
#define DD 512       // feature dim
#define TWO_N 8192
#define MT 64        // 8192/128 tiles per dim
#define NTILES 2080  // MT*(MT+1)/2
#define CHUNK 260    // NTILES/8 per XCD

using bf16x8 = __attribute__((ext_vector_type(8))) short;   // 8 bf16 in 4 VGPRs
using f32x4  = __attribute__((ext_vector_type(4))) float;

__device__ __forceinline__ unsigned short f2bf(float f) {
    union { float f; unsigned u; } v; v.f = f;
    unsigned r = v.u + 0x7fff + ((v.u >> 16) & 1);   // round-to-nearest-even
    return (unsigned short)(r >> 16);
}

// Kernel 1: L2-normalize rows of A and B -> bf16 X = [nA; nB], fp32 d12[i] = nA_i . nB_i.
// Also zeroes S[8192] (2 elements per block).
__global__ __launch_bounds__(256) void ntx_nrm_kernel(const float* __restrict__ A,
                                                      const float* __restrict__ B,
                                                      unsigned short* __restrict__ X,
                                                      float* __restrict__ d12,
                                                      float* __restrict__ S) {
    const int row = blockIdx.x;
    const int t = threadIdx.x;            // 256 threads, 2 elems each
    const int lane = t & 63, wid = t >> 6;

    if (t < 2) S[row * 2 + t] = 0.f;

    const float2 av = *(const float2*)(A + row * DD + 2 * t);
    const float2 bv = *(const float2*)(B + row * DD + 2 * t);
    float sa = av.x * av.x + av.y * av.y;
    float sb = bv.x * bv.x + bv.y * bv.y;
#pragma unroll
    for (int o = 32; o; o >>= 1) { sa += __shfl_down(sa, o); sb += __shfl_down(sb, o); }

    __shared__ float red[12];
    if (lane == 0) { red[wid] = sa; red[4 + wid] = sb; }
    __syncthreads();
    const float ta = red[0] + red[1] + red[2] + red[3];
    const float tb = red[4] + red[5] + red[6] + red[7];
    const float ra = 1.f / fmaxf(sqrtf(ta), 1e-8f);
    const float rb = 1.f / fmaxf(sqrtf(tb), 1e-8f);
    const float nax = av.x * ra, nay = av.y * ra;
    const float nbx = bv.x * rb, nby = bv.y * rb;

    *(unsigned*)(X + row * DD + 2 * t) =
        (unsigned)f2bf(nax) | ((unsigned)f2bf(nay) << 16);
    *(unsigned*)(X + (NR + row) * DD + 2 * t) =
        (unsigned)f2bf(nbx) | ((unsigned)f2bf(nby) << 16);

    float dt = nax * nbx + nay * nby;
#pragma unroll
    for (int o = 32; o; o >>= 1) dt += __shfl_down(dt, o);
    if (lane == 0) red[8 + wid] = dt;
    __syncthreads();
    if (t == 0) d12[row] = red[8] + red[9] + red[10] + red[11];
}

// Kernel 2: logits[r,c] = 2 * X_r . Z_c, Z_c = X_{c^4096}.
// Symmetry: compute only u<=v in (u,v)=(i, j^32) tile coords (2080 tiles),
// supertile-major + XCD-contiguous remap (round-7 verified).
// Round-11: 4-deep counted-vmcnt pipeline (BK=32, 4 x 8KB buffers per operand,
// 64 KB LDS): prefetch distance 4 covers ~900-cyc HBM-miss latency (round-10
// post-mortem: 2-deep left latency tails in every iter). Conflict-free slot
// swizzle kept (round-10, 0 conflicts). setprio removed (lockstep regime, m190).
__global__ __launch_bounds__(256) void ntx_gemm_lse_kernel(const unsigned short* __restrict__ X,
                                                           float* __restrict__ S) {
    // ---- bid -> XCD-contiguous supertile-ordered sid -> (u,v) ----
    const int bid = blockIdx.x;
    const int sid = (bid & 7) * CHUNK + (bid >> 3);
    int u, v;
    if (sid < 1792) {                    // off-diagonal supertile (U<V): 28 x 64
        const int s = sid >> 6, loc = sid & 63;
        int U = 0;
        while (7 * (U + 1) - (U + 1) * U / 2 <= s) ++U;      // offExcl(U+1) <= s
        const int V = U + 1 + (s - (7 * U - U * (U - 1) / 2));
        u = U * 8 + (loc >> 3);
        v = V * 8 + (loc & 7);
    } else {                             // diagonal supertile (U==V): 8 x 36, lu<=lv
        const int s2 = sid - 1792;
        const int U = s2 / 36, loc = s2 % 36;
        int lu = 0;
        while ((lu + 1) * 8 - (lu + 1) * lu / 2 <= loc) ++lu; // offIncl(lu+1) <= loc
        const int lv = lu + (loc - (lu * 8 - lu * (lu - 1) / 2));
        u = U * 8 + lu;
        v = U * 8 + lv;
    }
    const bool fixedTile = (u == v);
    const int rowTile = u * 128, colTile = (v ^ 32) * 128;

    __shared__ unsigned short As[4][128 * 32];   // 4 x 8 KB
    __shared__ unsigned short Bs[4][128 * 32];

    const int t = threadIdx.x;
    const int lane = t & 63, wid = t >> 6;
    const int waveRow = wid >> 1, waveCol = wid & 1;
    const int lr = lane & 15, grp = lane >> 4;
    const int swr = (lr >> 1) & 3;       // read-side swizzle key ((row>>1)&3)
    const int kslot = (grp ^ swr) * 8;   // physical 16B slot (ushorts) for this lane's frag

    f32x4 acc[4][4] = {};

    // staging: wave wid fills 1KB chunks ci=wid*2+q (16 rows of 64B).
    // lane l -> row = ci*16 + l/4, phys slot = l&3, LDS ushort idx = ci*512 + l*8.
    // inverse source swizzle: phys p at row r holds logical p^((r>>1)&3);
    // (r>>1)&3 = (l>>3)&3 here, so source col = kt + ((l&3)^((l>>3)&3))*8 elems.
    const int srow = lane >> 2;                              // 0..15 within chunk
    const int scol = ((lane & 3) ^ ((lane >> 3) & 3)) * 8;   // swizzled source col (elems)

    auto STAGE = [&](int sel, int kt) {  // 4 VMEM instructions per wave
#pragma unroll
        for (int q = 0; q < 2; ++q) {
            const int ci = wid * 2 + q;
            const int r  = ci * 16 + srow;
            const int lo = ci * 512 + lane * 8;       // ushort index of lane's 16B slot
            __builtin_amdgcn_global_load_lds(
                (const __attribute__((address_space(1))) unsigned*)(X + (size_t)(rowTile + r) * DD + kt + scol),
                (__attribute__((address_space(3))) unsigned*)&As[sel][lo], 16, 0, 0);
            __builtin_amdgcn_global_load_lds(
                (const __attribute__((address_space(1))) unsigned*)(X + (size_t)((colTile + r) ^ NR) * DD + kt + scol),
                (__attribute__((address_space(3))) unsigned*)&Bs[sel][lo], 16, 0, 0);
        }
    };

    auto COMPUTE = [&](int sel) {
        bf16x8 af[4], bfr[4];
#pragma unroll
        for (int m = 0; m < 4; ++m)
            af[m] = *(const bf16x8*)&As[sel][(waveRow * 64 + m * 16 + lr) * 32 + kslot];
#pragma unroll
        for (int n = 0; n < 4; ++n)
            bfr[n] = *(const bf16x8*)&Bs[sel][(waveCol * 64 + n * 16 + lr) * 32 + kslot];
#pragma unroll
        for (int m = 0; m < 4; ++m)
#pragma unroll
            for (int n = 0; n < 4; ++n)
                acc[m][n] = __builtin_amdgcn_mfma_f32_16x16x32_bf16(af[m], bfr[n], acc[m][n], 0, 0, 0);
    };

    // ---- 4-deep counted-vmcnt pipeline over 16 K-tiles (BK=32) ----
    STAGE(0, 0);
    STAGE(1, 32);
    STAGE(2, 64);
    STAGE(3, 96);                        // 16 loads outstanding (4 buffers)
#pragma unroll
    for (int i = 0; i < 16; ++i) {
        const int cur = i & 3;
        // buf[cur] ready when all loads newer than it may remain: 4*(15-i) capped at 12
        if (i <= 12)      asm volatile("s_waitcnt vmcnt(12)" ::: "memory");
        else if (i == 13) asm volatile("s_waitcnt vmcnt(8)"  ::: "memory");
        else if (i == 14) asm volatile("s_waitcnt vmcnt(4)"  ::: "memory");
        else              asm volatile("s_waitcnt vmcnt(0)"  ::: "memory");
        __builtin_amdgcn_s_barrier();    // all waves' buf[cur] writes landed
        COMPUTE(cur);
        if (i < 12) {
            asm volatile("s_waitcnt lgkmcnt(0)" ::: "memory");  // my ds_reads of buf[cur] done
            __builtin_amdgcn_s_barrier();                       // everyone's done reading buf[cur]
            STAGE(cur, (i + 4) * 32);    // refill 4 ahead; back to 16 outstanding
        }
    }

    // ---- Epilogue ----
    // C/D layout: col = lane&15 (lr), row = grp*4 + reg.
    // 1) in-place: acc <- exp(2*acc), masked to 0 on fixed-tile local diagonal
#pragma unroll
    for (int m = 0; m < 4; ++m)
#pragma unroll
        for (int n = 0; n < 4; ++n)
#pragma unroll
            for (int reg = 0; reg < 4; ++reg) {
                const int R = rowTile + waveRow * 64 + m * 16 + grp * 4 + reg;
                const int C = colTile + waveCol * 64 + n * 16 + lr;
                const bool masked = fixedTile && (C == (R ^ NR));
                acc[m][n][reg] = masked ? 0.f : __expf(acc[m][n][reg] * 2.0f);
            }

    // 2) row sums -> S[R]
#pragma unroll
    for (int m = 0; m < 4; ++m)
#pragma unroll
        for (int reg = 0; reg < 4; ++reg) {
            float rs = acc[m][0][reg] + acc[m][1][reg] + acc[m][2][reg] + acc[m][3][reg];
            rs += __shfl_xor(rs, 1);
            rs += __shfl_xor(rs, 2);
            rs += __shfl_xor(rs, 4);
            rs += __shfl_xor(rs, 8);
            if (lr == 0) {
                const int R = rowTile + waveRow * 64 + m * 16 + grp * 4 + reg;
                atomicAdd(&S[R], rs);
            }
        }

    // 3) mirror col sums -> S[C^N]  (skip on fixed tiles: they'd double-count)
    if (!fixedTile) {
#pragma unroll
        for (int n = 0; n < 4; ++n) {
            float cs = 0.f;
#pragma unroll
            for (int m = 0; m < 4; ++m)
#pragma unroll
                for (int reg = 0; reg < 4; ++reg)
                    cs += acc[m][n][reg];
            cs += __shfl_xor(cs, 16);
            cs += __shfl_xor(cs, 32);
            if (grp == 0) {
                const int C = colTile + waveCol * 64 + n * 16 + lr;
                atomicAdd(&S[C ^ NR], cs);
            }
        }
    }
}

// Kernel 3: loss = mean_r( log(S[r]) - 2*d12[r mod N] ), float32 scalar out.
__global__ __launch_bounds__(256) void ntx_loss_kernel(const float* __restrict__ S,
                                                       const float* __restrict__ d12,
                                                       float* __restrict__ out) {
    const int t = threadIdx.x;
    float a = 0.f;
    for (int r = t; r < TWO_N; r += 256)
        a += __logf(S[r]) - 2.0f * d12[r & (NR - 1)];
    const int lane = t & 63, wid = t >> 6;
#pragma unroll
    for (int o = 32; o; o >>= 1) a += __shfl_down(a, o);
    __shared__ float red[4];
    if (lane == 0) red[wid] = a;
    __syncthreads();
    if (t == 0) out[0] = (red[0] + red[1] + red[2] + red[3]) * (1.f / (float)TWO_N);
}

extern "C" void kernel_launch(void* const* d_in, const int* in_sizes, int n_in,
                              void* d_out, int out_size, void* d_ws, size_t ws_size,
                              hipStream_t stream) {
    const float* A = (const float*)d_in[0];
    const float* B = (const float*)d_in[1];

    // workspace layout
    unsigned short* X = (unsigned short*)d_ws;                    // 8192*512*2 = 8 MB
    float* S   = (float*)((char*)d_ws + (size_t)TWO_N * DD * 2);  // 32 KB
    float* d12 = (float*)((char*)S + (size_t)TWO_N * 4);          // 16 KB

    ntx_nrm_kernel<<<NR, 256, 0, stream>>>(A, B, X, d12, S);

    ntx_gemm_lse_kernel<<<NTILES, 256, 0, stream>>>(X, S);

    ntx_loss_kernel<<<1, 256, 0, stream>>>(S, d12, (float*)d_out);
}